// Round 11
// baseline (17898.515 us; speedup 1.0000x reference)
//
#include <hip/hip_runtime.h>
#include <hip/hip_bf16.h>

// BiLSTM-CRF on MI355X.  VOCAB=50000, EMB=256, HID=512 (H=256/dir), NTAG=20, SEQ=8192.
//
// Round-11: direction-interleaved LSTM scan.
// Rounds 3-10 established: the cross-CU h exchange costs ~2700cy and is
// invariant to protocol (LLC stores/polls r3/4/6, sc0 r5/8, wg-RMW r9/10).
// So pay it HALF as often: one 8-block group advances BOTH directions per
// superstep; the two directions' exchanges overlap each other and the
// compute. Block b owns h[b*32, b*32+32) for both dirs (weights 256 KB/CU,
// w[2][32] = 64 floats/thread). Per superstep: matvec d0+d1 (64 FMA/thread)
// -> B1 -> reducers (tid<256, gate-interleaved shfl cell update) publish
// both dirs ||| pollers (tid 256..703) poll both dirs -> B2.
// Exchange = r4-proven stamped agent-scope slots, parity double-buffered,
// zeroed each launch (replay-safe). No election, no handshake, no dual path.

#define S    8192
#define E    256
#define Hh   256          // per-direction hidden
#define G    1024         // 4*Hh gates
#define NT   20
#define NBI  8            // blocks (CUs), shared by both directions
#define NCHUNK 128        // 8192 / 64
#define CLEN   64

// ---------------------------------------------------------------- slot init
// slots: u64[2 dirs][2 parity][8 blocks][32 words] = 1024 u64 (8 KB)
__global__ __launch_bounds__(1024) void init_slots(unsigned long long* __restrict__ sl)
{
    sl[threadIdx.x] = 0ull;
}

// ---------------------------------------------------------------- xg projection
__global__ __launch_bounds__(1024, 4) void xg_project(
    const int* __restrict__ sent, const float* __restrict__ embed,
    const float* __restrict__ Wih_f, const float* __restrict__ bih_f, const float* __restrict__ bhh_f,
    const float* __restrict__ Wih_b, const float* __restrict__ bih_b, const float* __restrict__ bhh_b,
    float* __restrict__ xg)                       // [2][S][G]
{
    const int tb  = blockIdx.x;                   // 0..255 (32 timesteps each)
    const int rb  = blockIdx.y;                   // 0..3
    const int dir = blockIdx.z;                   // 0..1
    const int tid = threadIdx.x;
    const int q   = tid >> 8;                     // k-quarter 0..3
    const int idx = tid & 255;
    const int r   = rb * 256 + idx;               // gate row 0..1023
    const float* Wih = dir ? Wih_b : Wih_f;

    __shared__ __align__(16) float4 xs4[32 * 64]; // 32 timesteps x 256 floats (32 KB)
    __shared__ float psum[1024];

    const int t0 = tb * 32;
    #pragma unroll
    for (int i = 0; i < 2; ++i) {
        int qq  = i * 1024 + tid;                 // 2048 float4 total
        int row = qq >> 6;
        int c4  = qq & 63;
        int widx = sent[t0 + row];
        xs4[qq] = *(const float4*)(embed + (size_t)widx * E + (size_t)c4 * 4);
    }

    float w[64];
    #pragma unroll
    for (int k = 0; k < 64; k += 4) {
        float4 v = *(const float4*)(Wih + (size_t)r * E + q * 64 + k);
        w[k] = v.x; w[k+1] = v.y; w[k+2] = v.z; w[k+3] = v.w;
    }
    float bias = 0.f;
    if (tid < 256) bias = dir ? (bih_b[r] + bhh_b[r]) : (bih_f[r] + bhh_f[r]);
    __syncthreads();

    const float* xs = (const float*)xs4 + q * 64;
    float* outb = xg + ((size_t)dir * S + t0) * G + r;
    for (int tt = 0; tt < 32; ++tt) {
        float a0 = 0.f, a1 = 0.f, a2 = 0.f, a3 = 0.f;
        #pragma unroll
        for (int k = 0; k < 64; k += 4) {
            float4 h4 = *(const float4*)(xs + tt * E + k);   // LDS broadcast
            a0 = fmaf(w[k],   h4.x, a0);
            a1 = fmaf(w[k+1], h4.y, a1);
            a2 = fmaf(w[k+2], h4.z, a2);
            a3 = fmaf(w[k+3], h4.w, a3);
        }
        psum[tid] = (a0 + a1) + (a2 + a3);
        __syncthreads();
        if (tid < 256)
            outb[(size_t)tt * G] = bias +
                ((psum[idx] + psum[idx + 256]) + (psum[idx + 512] + psum[idx + 768]));
        __syncthreads();                          // psum reused next tt
    }
}

// ---------------------------------------------------------------- LSTM scan (interleaved dirs)
// 8 blocks, 1024 threads. Matvec mapping: kq = tid>>7 (k-chunk of 32),
// ridx = tid&127 -> gate = ridx&3, hloc = ridx>>2, row = gate*256+b*32+hloc.
// Reducers tid<256: d = tid>>7, rr = tid&127 (gate-interleaved; cell lane
// rg==0 via 3 shfl_down). Pollers tid 256..703: 2 dirs x 7 peers x 32 words.
__global__ __launch_bounds__(1024, 4) void lstm_scan_il(
    const float* __restrict__ xg,                 // [2][S][G]
    const float* __restrict__ Whh_f,
    const float* __restrict__ Whh_b,
    float* __restrict__ out,                      // [S][512]
    unsigned long long* __restrict__ slots)       // [2][2][8][32]
{
    const int b    = blockIdx.x;
    const int tid  = threadIdx.x;
    const int kq   = tid >> 7;                    // 0..7 (wave-uniform)
    const int ridx = tid & 127;
    const int gate = ridx & 3;
    const int hloc = ridx >> 2;
    const int row  = gate * Hh + b * 32 + hloc;

    float w0[32], w1[32];                         // quarter... 32-chunk per dir
    #pragma unroll
    for (int k = 0; k < 32; k += 4) {
        float4 v = *(const float4*)(Whh_f + (size_t)row * Hh + kq * 32 + k);
        w0[k] = v.x; w0[k+1] = v.y; w0[k+2] = v.z; w0[k+3] = v.w;
        float4 u = *(const float4*)(Whh_b + (size_t)row * Hh + kq * 32 + k);
        w1[k] = u.x; w1[k+1] = u.y; w1[k+2] = u.z; w1[k+3] = u.w;
    }

    __shared__ __align__(16) float h0[Hh], h1[Hh];
    __shared__ float ps0[1024], ps1[1024];
    if (tid < Hh) { h0[tid] = 0.f; h1[tid] = 0.f; }
    float cc = 0.f;                               // cell state (cell lanes only)

    // reducer role (tid<256): waves 0-1 = dir0 rows, waves 2-3 = dir1 rows
    const bool isRed = (tid < 256);
    const int  rd    = (tid >> 7) & 1;            // reducer's direction
    const int  rr    = tid & 127;
    const int  rg    = rr & 3;
    const int  rh    = rr >> 2;
    const int  rrow  = rg * Hh + b * 32 + rh;
    const int  rdt   = rd ? -1 : 1;
    const int  rt0   = rd ? (S - 1) : 0;
    const float* xgp = xg + (size_t)rd * S * G + rrow;

    // poller role (tid 256..703): pd = dir, 7 peers x 32 words each
    const bool isPol = (tid >= 256 && tid < 704);
    const int  pl    = tid - 256;
    const int  pd    = (pl >= 224) ? 1 : 0;
    const int  pq    = pd ? (pl - 224) : pl;
    const int  peer  = pq >> 5;                   // 0..6
    const int  word  = pq & 31;
    const int  pb    = peer + (peer >= b);        // peer block id

    float xg_c = 0.f, xg_n1 = 0.f;                // 2-deep prefetch (reducers)
    if (isRed) {
        xg_c  = xgp[(size_t)rt0 * G];
        xg_n1 = xgp[(size_t)(rt0 + rdt) * G];
    }
    __syncthreads();

    for (int s = 0; s < S; ++s) {
        float xg_n2 = 0.f;
        if (isRed && s + 2 < S)
            xg_n2 = xgp[(size_t)(rt0 + rdt * (s + 2)) * G];

        // matvec, both directions (h via wave-uniform LDS broadcast)
        const float* hp0 = (const float*)h0 + kq * 32;
        const float* hp1 = (const float*)h1 + kq * 32;
        float a0 = 0.f, a1 = 0.f, a2 = 0.f, a3 = 0.f;
        float b0 = 0.f, b1 = 0.f, b2 = 0.f, b3 = 0.f;
        #pragma unroll
        for (int k = 0; k < 32; k += 4) {
            float4 x4 = *(const float4*)(hp0 + k);
            a0 = fmaf(w0[k],   x4.x, a0);
            a1 = fmaf(w0[k+1], x4.y, a1);
            a2 = fmaf(w0[k+2], x4.z, a2);
            a3 = fmaf(w0[k+3], x4.w, a3);
            float4 y4 = *(const float4*)(hp1 + k);
            b0 = fmaf(w1[k],   y4.x, b0);
            b1 = fmaf(w1[k+1], y4.y, b1);
            b2 = fmaf(w1[k+2], y4.z, b2);
            b3 = fmaf(w1[k+3], y4.w, b3);
        }
        ps0[tid] = (a0 + a1) + (a2 + a3);
        ps1[tid] = (b0 + b1) + (b2 + b3);
        __syncthreads();                                     // B1: partials ready

        const unsigned st  = (unsigned)(s + 1);
        const int      par = s & 1;

        if (isRed) {
            const float* ps = rd ? ps1 : ps0;
            float s0 = ps[rr]       + ps[rr + 128];
            float s1 = ps[rr + 256] + ps[rr + 384];
            float s2 = ps[rr + 512] + ps[rr + 640];
            float s3 = ps[rr + 768] + ps[rr + 896];
            float acc = xg_c + ((s0 + s1) + (s2 + s3));
            float a = (rg == 2) ? tanhf(acc) : 1.f / (1.f + expf(-acc));
            float fv = __shfl_down(a, 1);
            float gv = __shfl_down(a, 2);
            float ov = __shfl_down(a, 3);
            if (rg == 0) {                                   // cell lane (i-gate)
                cc = fv * cc + a * gv;
                float h = ov * tanhf(cc);
                const int t = rt0 + rdt * s;
                unsigned long long pw = ((unsigned long long)st << 32) |
                                        (unsigned long long)__float_as_uint(h);
                __hip_atomic_store(&slots[((rd * 2 + par) * NBI + b) * 32 + rh],
                                   pw, __ATOMIC_RELAXED, __HIP_MEMORY_SCOPE_AGENT);
                out[(size_t)t * 512 + rd * Hh + b * 32 + rh] = h;
                (rd ? h1 : h0)[b * 32 + rh] = h;             // own chunk direct
            }
        } else if (isPol && s + 1 < S) {
            // poll peer pb's stamped word (both dirs' polls run concurrently
            // with the reducer tail above -> the two RTs overlap)
            unsigned long long* sp =
                &slots[((pd * 2 + par) * NBI + pb) * 32 + word];
            unsigned long long v;
            do {
                v = __hip_atomic_load(sp, __ATOMIC_RELAXED,
                                      __HIP_MEMORY_SCOPE_AGENT);
            } while ((unsigned)(v >> 32) != st);
            (pd ? h1 : h0)[pb * 32 + word] = __uint_as_float((unsigned)v);
        }
        __syncthreads();                                     // B2: h(t) in LDS
        xg_c = xg_n1; xg_n1 = xg_n2;
    }
}

// ---------------------------------------------------------------- emissions
__global__ __launch_bounds__(256) void emissions_kernel(
    const float* __restrict__ lo,                 // [S][512]
    const float* __restrict__ Wout,               // [NT][512]
    const float* __restrict__ bout,
    float* __restrict__ em)                       // [S][NT]
{
    int gid = blockIdx.x * blockDim.x + threadIdx.x;
    if (gid >= S * NT) return;
    int t = gid / NT;
    int j = gid - t * NT;
    const float* x = lo + (size_t)t * 512;
    const float* w = Wout + (size_t)j * 512;
    float a0 = 0.f, a1 = 0.f, a2 = 0.f, a3 = 0.f;
    #pragma unroll 8
    for (int k = 0; k < 512; k += 4) {
        float4 xv = *(const float4*)(x + k);
        float4 wv = *(const float4*)(w + k);
        a0 = fmaf(xv.x, wv.x, a0);
        a1 = fmaf(xv.y, wv.y, a1);
        a2 = fmaf(xv.z, wv.z, a2);
        a3 = fmaf(xv.w, wv.w, a3);
    }
    em[gid] = bout[j] + ((a0 + a1) + (a2 + a3));
}

// ---------------------------------------------------------------- viterbi forward
// 64 lanes: lane = g*20 + j (g=0..2 active, lanes 60..63 spectators).
__global__ __launch_bounds__(64) void viterbi_fwd(
    const float* __restrict__ em,                 // [S][NT]
    const float* __restrict__ start_trans,
    const float* __restrict__ end_trans,
    const float* __restrict__ trans,              // [NT][NT] (from,to)
    unsigned char* __restrict__ bp,               // [S][NT]
    int* __restrict__ last_out)
{
    const int lane = threadIdx.x;
    const int g    = lane / 20;                   // 0,1,2 (3 = spectator)
    const int j    = lane - g * 20;               // to-tag (0..19 for g<3)
    const int i0   = g * 7;

    float tc[7];
    #pragma unroll
    for (int u = 0; u < 7; ++u) {
        int i = i0 + u;
        tc[u] = (g < 3 && i < 20) ? trans[i * NT + j] : -3.0e38f;
    }

    const int jj = (g < 3) ? j : 0;               // safe index for spectators
    float snew  = start_trans[jj] + em[jj];       // score(0)
    if (g == 0) bp[j] = (unsigned char)j;         // t=0: identity (never used)
    float e_cur = em[NT + jj];

    for (int t = 1; t < S; ++t) {
        float s_sub[7];
        #pragma unroll
        for (int u = 0; u < 7; ++u)
            s_sub[u] = __shfl(snew, i0 + u);      // sources are lanes 0..27
        float e_nxt = (t + 1 < S) ? em[(size_t)(t + 1) * NT + jj] : 0.f;

        float bv = s_sub[0] + tc[0];
        int   bi = i0;
        #pragma unroll
        for (int u = 1; u < 7; ++u) {
            float v = s_sub[u] + tc[u];
            if (v > bv) { bv = v; bi = i0 + u; }  // strict >: first-index in group
        }
        float v0 = __shfl(bv, jj), v1 = __shfl(bv, jj + 20), v2 = __shfl(bv, jj + 40);
        int   c0 = __shfl(bi, jj), c1 = __shfl(bi, jj + 20), c2 = __shfl(bi, jj + 40);
        float best = v0; int bidx = c0;
        if (v1 > best) { best = v1; bidx = c1; }
        if (v2 > best) { best = v2; bidx = c2; }
        snew = best + e_cur;
        if (g == 0) bp[(size_t)t * NT + j] = (unsigned char)bidx;
        e_cur = e_nxt;
    }

    float bv = __shfl(snew, 0) + end_trans[0];
    int   bi = 0;
    #pragma unroll 1
    for (int i = 1; i < 20; ++i) {
        float v = __shfl(snew, i) + end_trans[i];
        if (v > bv) { bv = v; bi = i; }
    }
    if (lane == 0) *last_out = bi;
}

// ---------------------------------------------------------------- backtrace
__global__ __launch_bounds__(64) void bt_maps(
    const unsigned char* __restrict__ bp, unsigned char* __restrict__ maps)
{
    __shared__ unsigned char lbp[CLEN * NT];
    const int c = blockIdx.x, tid = threadIdx.x;
    const unsigned* src = (const unsigned*)(bp + (size_t)c * CLEN * NT);
    unsigned* dst = (unsigned*)lbp;
    for (int q = tid; q < CLEN * NT / 4; q += 64) dst[q] = src[q];
    __syncthreads();
    if (tid < NT) {
        int x = tid;
        for (int t = CLEN - 1; t >= 0; --t) x = lbp[t * NT + x];
        maps[c * NT + tid] = (unsigned char)x;
    }
}

__global__ __launch_bounds__(64) void bt_boundary(
    const unsigned char* __restrict__ maps, const int* __restrict__ last_out,
    int* __restrict__ btags)
{
    __shared__ unsigned char m[NCHUNK * NT];
    const int tid = threadIdx.x;
    for (int q = tid; q < NCHUNK * NT; q += 64) m[q] = maps[q];
    __syncthreads();
    if (tid == 0) {
        int x = *last_out;
        btags[NCHUNK - 1] = x;
        for (int c = NCHUNK - 1; c >= 1; --c) {
            x = m[c * NT + x];
            btags[c - 1] = x;
        }
    }
}

__global__ __launch_bounds__(64) void bt_emit(
    const unsigned char* __restrict__ bp, const int* __restrict__ btags,
    int* __restrict__ path)
{
    __shared__ unsigned char lbp[CLEN * NT];
    const int c = blockIdx.x, tid = threadIdx.x;
    const unsigned* src = (const unsigned*)(bp + (size_t)c * CLEN * NT);
    unsigned* dst = (unsigned*)lbp;
    for (int q = tid; q < CLEN * NT / 4; q += 64) dst[q] = src[q];
    __syncthreads();
    if (tid == 0) {
        int x = btags[c];
        path[c * CLEN + CLEN - 1] = x;
        for (int t = CLEN - 1; t >= 1; --t) {
            x = lbp[t * NT + x];
            path[c * CLEN + t - 1] = x;
        }
    }
}

// ---------------------------------------------------------------- launcher
extern "C" void kernel_launch(void* const* d_in, const int* in_sizes, int n_in,
                              void* d_out, int out_size, void* d_ws, size_t ws_size,
                              hipStream_t stream) {
    const int*   sent   = (const int*)  d_in[0];
    const float* embed  = (const float*)d_in[1];
    const float* Wih_f  = (const float*)d_in[2];
    const float* Whh_f  = (const float*)d_in[3];
    const float* bih_f  = (const float*)d_in[4];
    const float* bhh_f  = (const float*)d_in[5];
    const float* Wih_b  = (const float*)d_in[6];
    const float* Whh_b  = (const float*)d_in[7];
    const float* bih_b  = (const float*)d_in[8];
    const float* bhh_b  = (const float*)d_in[9];
    const float* Wout   = (const float*)d_in[10];
    const float* bout   = (const float*)d_in[11];
    const float* start_trans = (const float*)d_in[12];
    const float* end_trans   = (const float*)d_in[13];
    const float* trans       = (const float*)d_in[14];
    int* path = (int*)d_out;

    char* ws = (char*)d_ws;
    size_t off = 0;
    float* xg = (float*)(ws + off); off += (size_t)2 * S * G * 4;   // 64 MB
    float* lo = (float*)(ws + off); off += (size_t)S * 512 * 4;     // 16 MB
    float* em = (float*)(ws + off); off += (size_t)S * NT * 4;      // 640 KB
    unsigned char* bp   = (unsigned char*)(ws + off); off += (size_t)S * NT;  // 160 KB
    unsigned char* maps = (unsigned char*)(ws + off); off += 4096;
    int* btags = (int*)(ws + off); off += 1024;
    int* lastp = (int*)(ws + off); off += 256;
    off = (off + 255) & ~(size_t)255;
    unsigned long long* slots = (unsigned long long*)(ws + off); off += 1024 * 8;

    init_slots<<<dim3(1), 1024, 0, stream>>>(slots);
    xg_project<<<dim3(S / 32, 4, 2), 1024, 0, stream>>>(
        sent, embed, Wih_f, bih_f, bhh_f, Wih_b, bih_b, bhh_b, xg);
    lstm_scan_il<<<dim3(NBI), 1024, 0, stream>>>(xg, Whh_f, Whh_b, lo, slots);
    emissions_kernel<<<dim3((S * NT + 255) / 256), 256, 0, stream>>>(lo, Wout, bout, em);
    viterbi_fwd<<<dim3(1), 64, 0, stream>>>(em, start_trans, end_trans, trans, bp, lastp);
    bt_maps<<<dim3(NCHUNK), 64, 0, stream>>>(bp, maps);
    bt_boundary<<<dim3(1), 64, 0, stream>>>(maps, lastp, btags);
    bt_emit<<<dim3(NCHUNK), 64, 0, stream>>>(bp, btags, path);
}

// Round 12
// 16267.192 us; speedup vs baseline: 1.1003x; 1.1003x over previous
//
#include <hip/hip_runtime.h>
#include <hip/hip_bf16.h>

// BiLSTM-CRF on MI355X.  VOCAB=50000, EMB=256, HID=512 (H=256/dir), NTAG=20, SEQ=8192.
//
// Round-12: revert scan to the round-4 optimum (13.4 ms, best of 9 variants;
// the cross-CU exchange is a ~2500cy HW constant, invariant to protocol) and
// attack the second-biggest kernel: viterbi_fwd (~1.5 ms, est. 500cy/iter
// from chained shuffle levels). New viterbi: single wave, lane j owns score
// j; per iteration one ds_write + five uniform ds_read_b128 (same-wave LDS
// ops are ordered -> no barrier) + in-register 19-combine argmax tree with
// strict-> index-ordered combines (== first-index linear scan semantics).

#define S    8192
#define E    256
#define Hh   256          // per-direction hidden
#define G    1024         // 4*Hh gates
#define NT   20
#define NB   4            // blocks (CUs) per direction
#define NCHUNK 128        // 8192 / 64
#define CLEN   64
#define SENT 0x7FC0DEADu  // NaN bit pattern; h values are never NaN

// ---------------------------------------------------------------- sentinel fill
__global__ __launch_bounds__(256) void sentinel_fill(unsigned int* __restrict__ lo_u)
{
    size_t base = (size_t)blockIdx.x * 1024 + threadIdx.x;
    #pragma unroll
    for (int i = 0; i < 4; ++i)
        __hip_atomic_store(&lo_u[base + (size_t)i * 256], SENT,
                           __ATOMIC_RELAXED, __HIP_MEMORY_SCOPE_AGENT);
}

// ---------------------------------------------------------------- xg projection
__global__ __launch_bounds__(1024, 4) void xg_project(
    const int* __restrict__ sent, const float* __restrict__ embed,
    const float* __restrict__ Wih_f, const float* __restrict__ bih_f, const float* __restrict__ bhh_f,
    const float* __restrict__ Wih_b, const float* __restrict__ bih_b, const float* __restrict__ bhh_b,
    float* __restrict__ xg)                       // [2][S][G]
{
    const int tb  = blockIdx.x;                   // 0..255 (32 timesteps each)
    const int rb  = blockIdx.y;                   // 0..3
    const int dir = blockIdx.z;                   // 0..1
    const int tid = threadIdx.x;
    const int q   = tid >> 8;                     // k-quarter 0..3
    const int idx = tid & 255;
    const int r   = rb * 256 + idx;               // gate row 0..1023
    const float* Wih = dir ? Wih_b : Wih_f;

    __shared__ __align__(16) float4 xs4[32 * 64]; // 32 timesteps x 256 floats (32 KB)
    __shared__ float psum[1024];

    const int t0 = tb * 32;
    #pragma unroll
    for (int i = 0; i < 2; ++i) {
        int qq  = i * 1024 + tid;                 // 2048 float4 total
        int row = qq >> 6;
        int c4  = qq & 63;
        int widx = sent[t0 + row];
        xs4[qq] = *(const float4*)(embed + (size_t)widx * E + (size_t)c4 * 4);
    }

    float w[64];
    #pragma unroll
    for (int k = 0; k < 64; k += 4) {
        float4 v = *(const float4*)(Wih + (size_t)r * E + q * 64 + k);
        w[k] = v.x; w[k+1] = v.y; w[k+2] = v.z; w[k+3] = v.w;
    }
    float bias = 0.f;
    if (tid < 256) bias = dir ? (bih_b[r] + bhh_b[r]) : (bih_f[r] + bhh_f[r]);
    __syncthreads();

    const float* xs = (const float*)xs4 + q * 64;
    float* outb = xg + ((size_t)dir * S + t0) * G + r;
    for (int tt = 0; tt < 32; ++tt) {
        float a0 = 0.f, a1 = 0.f, a2 = 0.f, a3 = 0.f;
        #pragma unroll
        for (int k = 0; k < 64; k += 4) {
            float4 h4 = *(const float4*)(xs + tt * E + k);   // LDS broadcast
            a0 = fmaf(w[k],   h4.x, a0);
            a1 = fmaf(w[k+1], h4.y, a1);
            a2 = fmaf(w[k+2], h4.z, a2);
            a3 = fmaf(w[k+3], h4.w, a3);
        }
        psum[tid] = (a0 + a1) + (a2 + a3);
        __syncthreads();
        if (tid < 256)
            outb[(size_t)tt * G] = bias +
                ((psum[idx] + psum[idx + 256]) + (psum[idx + 512] + psum[idx + 768]));
        __syncthreads();                          // psum reused next tt
    }
}

// ---------------------------------------------------------------- LSTM scan (exact round-4)
__global__ __launch_bounds__(1024, 4) void lstm_scan_mc(
    const float* __restrict__ xg,                 // [2][S][G]
    const float* __restrict__ Whh_f,
    const float* __restrict__ Whh_b,
    float* __restrict__ out)                      // [S][512], sentinel-prefilled
{
    const int b    = blockIdx.x;
    const int dir  = blockIdx.y;
    const int tid  = threadIdx.x;
    const int q    = tid >> 8;
    const int idx  = tid & 255;
    const int gate = idx >> 6;
    const int hloc = idx & 63;
    const int hidx = b * 64 + hloc;
    const int row  = gate * Hh + hidx;
    const float* W   = dir ? Whh_b : Whh_f;
    const float* xgd = xg + (size_t)dir * S * G;

    float w[64];
    #pragma unroll
    for (int k = 0; k < 64; k += 4) {
        float4 v = *(const float4*)(W + (size_t)row * Hh + q * 64 + k);
        w[k] = v.x; w[k+1] = v.y; w[k+2] = v.z; w[k+3] = v.w;
    }

    __shared__ __align__(16) float h_lds[Hh];
    __shared__ float psum[1024];
    __shared__ float gates_lds[256];
    if (tid < Hh) h_lds[tid] = 0.f;
    float c = 0.f;

    const int t0 = dir ? (S - 1) : 0;
    const int dt = dir ? -1 : 1;
    float xg_cur = (tid < 256) ? xgd[(size_t)t0 * G + row] : 0.f;
    __syncthreads();

    for (int s = 0; s < S; ++s) {
        const int t = t0 + dt * s;
        float xg_next = 0.f;
        if (tid < 256 && s + 1 < S) xg_next = xgd[(size_t)(t + dt) * G + row];

        // partial matvec over this thread's k-quarter (wave-uniform LDS bcast)
        const float* hh = (const float*)h_lds + q * 64;
        float a0 = 0.f, a1 = 0.f, a2 = 0.f, a3 = 0.f;
        #pragma unroll
        for (int k = 0; k < 64; k += 4) {
            float4 h4 = *(const float4*)(hh + k);
            a0 = fmaf(w[k],   h4.x, a0);
            a1 = fmaf(w[k+1], h4.y, a1);
            a2 = fmaf(w[k+2], h4.z, a2);
            a3 = fmaf(w[k+3], h4.w, a3);
        }
        psum[tid] = (a0 + a1) + (a2 + a3);
        __syncthreads();                                     // partials ready

        if (tid < 256) {
            float acc = xg_cur +
                ((psum[idx] + psum[idx + 256]) + (psum[idx + 512] + psum[idx + 768]));
            float a = (gate == 2) ? tanhf(acc) : 1.f / (1.f + expf(-acc));
            gates_lds[idx] = a;
        }
        __syncthreads();                                     // gates ready

        if (tid < 64) {                                      // wave 0: cell update
            float iv = gates_lds[hloc];
            float fv = gates_lds[64 + hloc];
            float gv = gates_lds[128 + hloc];
            float ov = gates_lds[192 + hloc];
            c = fv * c + iv * gv;
            float h = ov * tanhf(c);
            __hip_atomic_store(out + (size_t)t * 512 + dir * Hh + hidx, h,
                               __ATOMIC_RELAXED, __HIP_MEMORY_SCOPE_AGENT);
            h_lds[hidx] = h;                                 // own segment direct
        }
        // poll peers' h words (written exactly once; never the NaN sentinel)
        if (s + 1 < S && tid < Hh && (tid >> 6) != b) {
            const unsigned int* srcp =
                (const unsigned int*)(out + (size_t)t * 512 + dir * Hh + tid);
            unsigned int v;
            do {
                v = __hip_atomic_load(srcp, __ATOMIC_RELAXED,
                                      __HIP_MEMORY_SCOPE_AGENT);
            } while (v == SENT);
            h_lds[tid] = __uint_as_float(v);
        }
        __syncthreads();                                     // h(t) complete in LDS
        xg_cur = xg_next;
    }
}

// ---------------------------------------------------------------- emissions
__global__ __launch_bounds__(256) void emissions_kernel(
    const float* __restrict__ lo,                 // [S][512]
    const float* __restrict__ Wout,               // [NT][512]
    const float* __restrict__ bout,
    float* __restrict__ em)                       // [S][NT]
{
    int gid = blockIdx.x * blockDim.x + threadIdx.x;
    if (gid >= S * NT) return;
    int t = gid / NT;
    int j = gid - t * NT;
    const float* x = lo + (size_t)t * 512;
    const float* w = Wout + (size_t)j * 512;
    float a0 = 0.f, a1 = 0.f, a2 = 0.f, a3 = 0.f;
    #pragma unroll 8
    for (int k = 0; k < 512; k += 4) {
        float4 xv = *(const float4*)(x + k);
        float4 wv = *(const float4*)(w + k);
        a0 = fmaf(xv.x, wv.x, a0);
        a1 = fmaf(xv.y, wv.y, a1);
        a2 = fmaf(xv.z, wv.z, a2);
        a3 = fmaf(xv.w, wv.w, a3);
    }
    em[gid] = bout[j] + ((a0 + a1) + (a2 + a3));
}

// ---------------------------------------------------------------- viterbi forward
// Single wave, no barriers. Lane j (<20) owns score j. Per iteration:
// ds_write snew -> 5 uniform ds_read_b128 (same-wave LDS ops are ordered) ->
// 20 adds -> 19-combine argmax tree. Tree combines are index-ordered with
// strict > (take right only if strictly greater) == linear first-index scan.
__device__ __forceinline__ void vit_cmb(float& va, int& ia, float vb, int ib) {
    if (vb > va) { va = vb; ia = ib; }
}

__global__ __launch_bounds__(64) void viterbi_fwd(
    const float* __restrict__ em,                 // [S][NT]
    const float* __restrict__ start_trans,
    const float* __restrict__ end_trans,
    const float* __restrict__ trans,              // [NT][NT] (from,to)
    unsigned char* __restrict__ bp,               // [S][NT]
    int* __restrict__ last_out)
{
    const int lane = threadIdx.x;
    const bool act = (lane < NT);
    const int j = act ? lane : 0;                 // spectators mirror lane 0

    __shared__ __align__(16) float sc[24];        // score vector (single wave)

    float tc[NT];                                 // trans column j
    #pragma unroll
    for (int i = 0; i < NT; ++i) tc[i] = trans[i * NT + j];

    float snew = start_trans[j] + em[j];          // score(0), lane-local
    if (act) bp[lane] = (unsigned char)lane;      // t=0: identity (never used)
    float e0 = em[NT + j];                        // em(1)
    float e1 = em[2 * NT + j];                    // em(2)

    for (int t = 1; t < S; ++t) {
        if (act) sc[lane] = snew;                 // ds_write
        __builtin_amdgcn_wave_barrier();          // keep LDS op order (free)
        float s0[NT];
        #pragma unroll
        for (int i = 0; i < NT; i += 4) {         // 5 uniform b128 reads
            float4 v = *(const float4*)(sc + i);
            s0[i] = v.x; s0[i+1] = v.y; s0[i+2] = v.z; s0[i+3] = v.w;
        }
        __builtin_amdgcn_wave_barrier();          // reads before next write

        float e2 = (t + 2 < S) ? em[(size_t)(t + 2) * NT + j] : 0.f;

        float cv[NT];
        #pragma unroll
        for (int i = 0; i < NT; ++i) cv[i] = s0[i] + tc[i];

        // argmax tree (first-index ties): L1 10, L2 5, L3 2+carry, L4, L5
        float v1[10]; int i1[10];
        #pragma unroll
        for (int u = 0; u < 10; ++u) {
            v1[u] = cv[2*u]; i1[u] = 2*u;
            vit_cmb(v1[u], i1[u], cv[2*u+1], 2*u+1);
        }
        float v2[5]; int i2[5];
        #pragma unroll
        for (int u = 0; u < 5; ++u) {
            v2[u] = v1[2*u]; i2[u] = i1[2*u];
            vit_cmb(v2[u], i2[u], v1[2*u+1], i1[2*u+1]);
        }
        float v3a = v2[0]; int i3a = i2[0];
        vit_cmb(v3a, i3a, v2[1], i2[1]);
        float v3b = v2[2]; int i3b = i2[2];
        vit_cmb(v3b, i3b, v2[3], i2[3]);
        vit_cmb(v3a, i3a, v3b, i3b);              // covers 0..15
        vit_cmb(v3a, i3a, v2[4], i2[4]);          // 16..19 last (index order)

        snew = v3a + e0;
        if (act) bp[(size_t)t * NT + lane] = (unsigned char)i3a;
        e0 = e1; e1 = e2;
    }

    // final: + end_trans, first-index argmax
    if (act) sc[lane] = snew + end_trans[j];
    __builtin_amdgcn_wave_barrier();
    {
        float s0[NT];
        #pragma unroll
        for (int i = 0; i < NT; i += 4) {
            float4 v = *(const float4*)(sc + i);
            s0[i] = v.x; s0[i+1] = v.y; s0[i+2] = v.z; s0[i+3] = v.w;
        }
        float bv = s0[0]; int bi = 0;
        #pragma unroll
        for (int i = 1; i < NT; ++i) vit_cmb(bv, bi, s0[i], i);
        if (lane == 0) *last_out = bi;
    }
}

// ---------------------------------------------------------------- backtrace
__global__ __launch_bounds__(64) void bt_maps(
    const unsigned char* __restrict__ bp, unsigned char* __restrict__ maps)
{
    __shared__ unsigned char lbp[CLEN * NT];
    const int c = blockIdx.x, tid = threadIdx.x;
    const unsigned* src = (const unsigned*)(bp + (size_t)c * CLEN * NT);
    unsigned* dst = (unsigned*)lbp;
    for (int q = tid; q < CLEN * NT / 4; q += 64) dst[q] = src[q];
    __syncthreads();
    if (tid < NT) {
        int x = tid;
        for (int t = CLEN - 1; t >= 0; --t) x = lbp[t * NT + x];
        maps[c * NT + tid] = (unsigned char)x;
    }
}

__global__ __launch_bounds__(64) void bt_boundary(
    const unsigned char* __restrict__ maps, const int* __restrict__ last_out,
    int* __restrict__ btags)
{
    __shared__ unsigned char m[NCHUNK * NT];
    const int tid = threadIdx.x;
    for (int q = tid; q < NCHUNK * NT; q += 64) m[q] = maps[q];
    __syncthreads();
    if (tid == 0) {
        int x = *last_out;
        btags[NCHUNK - 1] = x;
        for (int c = NCHUNK - 1; c >= 1; --c) {
            x = m[c * NT + x];
            btags[c - 1] = x;
        }
    }
}

__global__ __launch_bounds__(64) void bt_emit(
    const unsigned char* __restrict__ bp, const int* __restrict__ btags,
    int* __restrict__ path)
{
    __shared__ unsigned char lbp[CLEN * NT];
    const int c = blockIdx.x, tid = threadIdx.x;
    const unsigned* src = (const unsigned*)(bp + (size_t)c * CLEN * NT);
    unsigned* dst = (unsigned*)lbp;
    for (int q = tid; q < CLEN * NT / 4; q += 64) dst[q] = src[q];
    __syncthreads();
    if (tid == 0) {
        int x = btags[c];
        path[c * CLEN + CLEN - 1] = x;
        for (int t = CLEN - 1; t >= 1; --t) {
            x = lbp[t * NT + x];
            path[c * CLEN + t - 1] = x;
        }
    }
}

// ---------------------------------------------------------------- launcher
extern "C" void kernel_launch(void* const* d_in, const int* in_sizes, int n_in,
                              void* d_out, int out_size, void* d_ws, size_t ws_size,
                              hipStream_t stream) {
    const int*   sent   = (const int*)  d_in[0];
    const float* embed  = (const float*)d_in[1];
    const float* Wih_f  = (const float*)d_in[2];
    const float* Whh_f  = (const float*)d_in[3];
    const float* bih_f  = (const float*)d_in[4];
    const float* bhh_f  = (const float*)d_in[5];
    const float* Wih_b  = (const float*)d_in[6];
    const float* Whh_b  = (const float*)d_in[7];
    const float* bih_b  = (const float*)d_in[8];
    const float* bhh_b  = (const float*)d_in[9];
    const float* Wout   = (const float*)d_in[10];
    const float* bout   = (const float*)d_in[11];
    const float* start_trans = (const float*)d_in[12];
    const float* end_trans   = (const float*)d_in[13];
    const float* trans       = (const float*)d_in[14];
    int* path = (int*)d_out;

    char* ws = (char*)d_ws;
    size_t off = 0;
    float* xg = (float*)(ws + off); off += (size_t)2 * S * G * 4;   // 64 MB
    float* lo = (float*)(ws + off); off += (size_t)S * 512 * 4;     // 16 MB
    float* em = (float*)(ws + off); off += (size_t)S * NT * 4;      // 640 KB
    unsigned char* bp   = (unsigned char*)(ws + off); off += (size_t)S * NT;  // 160 KB
    unsigned char* maps = (unsigned char*)(ws + off); off += 4096;
    int* btags = (int*)(ws + off); off += 1024;
    int* lastp = (int*)(ws + off); off += 256;

    sentinel_fill<<<dim3(4096), 256, 0, stream>>>((unsigned int*)lo);
    xg_project<<<dim3(S / 32, 4, 2), 1024, 0, stream>>>(
        sent, embed, Wih_f, bih_f, bhh_f, Wih_b, bih_b, bhh_b, xg);
    lstm_scan_mc<<<dim3(NB, 2), 1024, 0, stream>>>(xg, Whh_f, Whh_b, lo);
    emissions_kernel<<<dim3((S * NT + 255) / 256), 256, 0, stream>>>(lo, Wout, bout, em);
    viterbi_fwd<<<dim3(1), 64, 0, stream>>>(em, start_trans, end_trans, trans, bp, lastp);
    bt_maps<<<dim3(NCHUNK), 64, 0, stream>>>(bp, maps);
    bt_boundary<<<dim3(1), 64, 0, stream>>>(maps, lastp, btags);
    bt_emit<<<dim3(NCHUNK), 64, 0, stream>>>(bp, btags, path);
}